// Round 5
// baseline (225.118 us; speedup 1.0000x reference)
//
#include <hip/hip_runtime.h>
#include <math.h>

#define SEQ   8192
#define DIM   2048
#define NH    16
#define DH    128
#define PD    512

static constexpr float LN_EPS = 1e-5f;
static constexpr float SCALE  = 0.08838834764831845f; // 1/sqrt(128)

typedef __bf16 bf16x8 __attribute__((ext_vector_type(8)));
typedef float  f32x4  __attribute__((ext_vector_type(4)));

// ---- workspace layout (in floats); all offsets multiple of 4 (16B aligned) ----
static constexpr size_t OFF_QB   = 0;                         // 16
static constexpr size_t OFF_SMP  = 16;                        // 512 = smp[h][32] exp-sum partials
static constexpr size_t OFF_QWB  = 528;                       // 16*2048 bf16 = 16384 floats
static constexpr size_t OFF_PCTX = OFF_QWB + 16384;           // 256*16*2048
static constexpr size_t OFF_CTX  = OFF_PCTX + 256*32768;      // 16*2048
static constexpr size_t OFF_X1   = OFF_CTX + 32768;           // 2048
static constexpr size_t OFF_H1R  = OFF_X1 + 2048;             // 512
static constexpr size_t OFF_X1F  = OFF_H1R + 512;             // 2048

// qWb[h][j] = bf16( sum_d q[h*128+d]*W_kv[(h*128+d)*DIM+j] ); qb[h]; zero smp.
// grid 256 = (h 16) x (jc 16); 256 thr: col = t&127, k-half = t>>7
__global__ __launch_bounds__(256) void k_prep(const float* __restrict__ q,
                                              const float* __restrict__ Wkv,
                                              const float* __restrict__ bkv,
                                              __bf16* __restrict__ qWb,
                                              float* __restrict__ qb,
                                              float* __restrict__ smp) {
    int t = threadIdx.x;
    int h = blockIdx.x >> 4, jc = blockIdx.x & 15;
    int col = t & 127, kh = t >> 7;
    int j = jc * 128 + col;
    const float* w  = Wkv + (size_t)(h * DH + kh * 64) * DIM + j;
    const float* qh = q + h * DH + kh * 64;
    float acc = 0.f;
#pragma unroll 16
    for (int d = 0; d < 64; ++d)
        acc += qh[d] * w[(size_t)d * DIM];
    __shared__ float part[128];
    if (kh) part[col] = acc;
    __syncthreads();
    if (!kh) qWb[h * DIM + j] = (__bf16)(acc + part[col]);
    if (jc == 0 && t < 64) {
        float p = q[h*DH + t] * bkv[h*DH + t] + q[h*DH + 64 + t] * bkv[h*DH + 64 + t];
        for (int off = 32; off; off >>= 1) p += __shfl_down(p, off);
        if (t == 0) qb[h] = p;
    }
    if (blockIdx.x == 0) { smp[t] = 0.f; smp[t + 256] = 0.f; }
}

// Fused attention: per block of 32 s-rows:
//  phase 1: MFMA logits -> elog (unnormalized exp) in LDS + per-head partial sums
//  phase 2: pctx[b][h][j] = sum_{s in block} elog[s][h] * x[s][j]  (x re-read, L2-warm)
// grid 256, 256 thr = 4 waves: wave = (row-tile w>>1) x (K-half w&1), 32 MFMA each.
__global__ __launch_bounds__(256) void k_attn(const float* __restrict__ x,
                                              const __bf16* __restrict__ qWb,
                                              const float* __restrict__ qb,
                                              float* __restrict__ pctx,
                                              float* __restrict__ smp) {
    const int t = threadIdx.x;
    const int w = t >> 6, lane = t & 63;
    const int r = lane & 15, quad = lane >> 4;
    const int s0 = blockIdx.x * 32;
    const int tile = w >> 1, kh = w & 1;
    __shared__ float dpart[4][64][4];
    __shared__ float att[32][NH];
    __shared__ float hsum[NH];
    if (t < NH) hsum[t] = 0.f;

    // ---- phase 1: logits via MFMA (A = x rows fp32->bf16 otf, B = qWb) ----
    const float*  xrow = x + (size_t)(s0 + tile * 16 + r) * DIM + quad * 8;
    const __bf16* brow = qWb + r * DIM + quad * 8;  // r doubles as h for B
    const int kbase = kh * 1024;
    f32x4 acc0 = {0.f, 0.f, 0.f, 0.f}, acc1 = {0.f, 0.f, 0.f, 0.f};
#pragma unroll 4
    for (int i = 0; i < 16; ++i) {
        int k = kbase + i * 64;
        {
            float4 xa = *(const float4*)(xrow + k);
            float4 xb = *(const float4*)(xrow + k + 4);
            bf16x8 af;
            af[0]=(__bf16)xa.x; af[1]=(__bf16)xa.y; af[2]=(__bf16)xa.z; af[3]=(__bf16)xa.w;
            af[4]=(__bf16)xb.x; af[5]=(__bf16)xb.y; af[6]=(__bf16)xb.z; af[7]=(__bf16)xb.w;
            bf16x8 bfv = *(const bf16x8*)(brow + k);
            acc0 = __builtin_amdgcn_mfma_f32_16x16x32_bf16(af, bfv, acc0, 0, 0, 0);
        }
        {
            float4 xa = *(const float4*)(xrow + k + 32);
            float4 xb = *(const float4*)(xrow + k + 36);
            bf16x8 af;
            af[0]=(__bf16)xa.x; af[1]=(__bf16)xa.y; af[2]=(__bf16)xa.z; af[3]=(__bf16)xa.w;
            af[4]=(__bf16)xb.x; af[5]=(__bf16)xb.y; af[6]=(__bf16)xb.z; af[7]=(__bf16)xb.w;
            bf16x8 bfv = *(const bf16x8*)(brow + k + 32);
            acc1 = __builtin_amdgcn_mfma_f32_16x16x32_bf16(af, bfv, acc1, 0, 0, 0);
        }
    }
    dpart[w][lane][0] = acc0[0] + acc1[0];
    dpart[w][lane][1] = acc0[1] + acc1[1];
    dpart[w][lane][2] = acc0[2] + acc1[2];
    dpart[w][lane][3] = acc0[3] + acc1[3];
    __syncthreads();
    {   // combine K-halves; D layout: h = lane2&15, s_local = (lane2>>4)*4 + reg
        const int lane2 = t & 63, reg = t >> 6;
        const int h = lane2 & 15, sl = (lane2 >> 4) * 4 + reg;
        float v0 = dpart[0][lane2][reg] + dpart[1][lane2][reg];
        float e0 = __expf((v0 + qb[h]) * SCALE);   // no max-sub: |logit| <~ 5
        att[sl][h] = e0;
        float v1 = dpart[2][lane2][reg] + dpart[3][lane2][reg];
        float e1 = __expf((v1 + qb[h]) * SCALE);
        att[16 + sl][h] = e1;
        atomicAdd(&hsum[h], e0 + e1);
    }
    __syncthreads();
    if (t < NH) atomicAdd(&smp[t * 32 + (blockIdx.x & 31)], hsum[t]);

    // ---- phase 2: pctx accumulation (unnormalized); 2 col-passes of 1024 ----
#pragma unroll
    for (int jc = 0; jc < 2; ++jc) {
        int j = jc * 1024 + t * 4;
        float4 acc[NH];
#pragma unroll
        for (int h = 0; h < NH; ++h) acc[h] = make_float4(0.f, 0.f, 0.f, 0.f);
        for (int rr = 0; rr < 32; ++rr) {
            float4 xv = *(const float4*)&x[(size_t)(s0 + rr) * DIM + j];
            const float4* ar = (const float4*)att[rr];   // broadcast LDS reads
            float4 a0 = ar[0], a1 = ar[1], a2 = ar[2], a3 = ar[3];
            float aa[NH];
            *(float4*)&aa[0] = a0; *(float4*)&aa[4]  = a1;
            *(float4*)&aa[8] = a2; *(float4*)&aa[12] = a3;
#pragma unroll
            for (int h = 0; h < NH; ++h) {
                acc[h].x += aa[h] * xv.x;
                acc[h].y += aa[h] * xv.y;
                acc[h].z += aa[h] * xv.z;
                acc[h].w += aa[h] * xv.w;
            }
        }
#pragma unroll
        for (int h = 0; h < NH; ++h)
            *(float4*)&pctx[((size_t)(blockIdx.x * NH + h)) * DIM + j] = acc[h];
    }
}

// ctx[idx] = (sum_{sc<256} pctx[sc][idx]) / S[h],  h = idx>>11
__global__ __launch_bounds__(256) void k_ctxred(const float* __restrict__ pctx,
                                                const float* __restrict__ smp,
                                                float* __restrict__ ctx) {
    int idx = blockIdx.x * 256 + threadIdx.x; // 0..32767
    int h = idx >> 11;
    float S = 0.f;
#pragma unroll
    for (int i = 0; i < 32; ++i) S += smp[h * 32 + i];
    float s = 0.f;
#pragma unroll 8
    for (int sc = 0; sc < 256; ++sc)
        s += pctx[(size_t)sc * (NH * DIM) + idx];
    ctx[idx] = s / S;
}

// x1[row] = ctx[row>>7]·W_v[row] + b_kv[DIM+row]; one wave/row, 4 rows/block
__global__ __launch_bounds__(256) void k_x1(const float* __restrict__ Wkv,
                                            const float* __restrict__ bkv,
                                            const float* __restrict__ ctx,
                                            float* __restrict__ x1) {
    int row = blockIdx.x * 4 + (threadIdx.x >> 6);
    int lane = threadIdx.x & 63;
    const float* w = Wkv + (size_t)(DIM + row) * DIM;
    const float* c = ctx + (row >> 7) * DIM;
    float acc = 0.f;
#pragma unroll
    for (int k = 0; k < 8; ++k) {
        int j = k * 256 + lane * 4;
        float4 wv = *(const float4*)&w[j];
        float4 cv = *(const float4*)&c[j];
        acc += wv.x*cv.x + wv.y*cv.y + wv.z*cv.z + wv.w*cv.w;
    }
    for (int off = 32; off; off >>= 1) acc += __shfl_xor(acc, off);
    if (lane == 0) x1[row] = acc + bkv[DIM + row];
}

// h1raw[row] = x1·W_p1[row] + b_p1[row]
__global__ __launch_bounds__(256) void k_h1(const float* __restrict__ Wp1,
                                            const float* __restrict__ bp1,
                                            const float* __restrict__ x1,
                                            float* __restrict__ h1raw) {
    int row = blockIdx.x * 4 + (threadIdx.x >> 6);
    int lane = threadIdx.x & 63;
    const float* w = Wp1 + (size_t)row * DIM;
    float acc = 0.f;
#pragma unroll
    for (int k = 0; k < 8; ++k) {
        int j = k * 256 + lane * 4;
        float4 wv = *(const float4*)&w[j];
        float4 cv = *(const float4*)&x1[j];
        acc += wv.x*cv.x + wv.y*cv.y + wv.z*cv.z + wv.w*cv.w;
    }
    for (int off = 32; off; off >>= 1) acc += __shfl_xor(acc, off);
    if (lane == 0) h1raw[row] = acc + bp1[row];
}

// Fused LN+relu+proj2: x1f[row] = relu(LN(h1raw))·W_p2[row] + b_p2[row]
__global__ __launch_bounds__(256) void k_x1f(const float* __restrict__ Wp2,
                                             const float* __restrict__ bp2,
                                             const float* __restrict__ h1raw,
                                             const float* __restrict__ lnw,
                                             const float* __restrict__ lnb,
                                             float* __restrict__ x1f) {
    int row = blockIdx.x * 4 + (threadIdx.x >> 6);
    int lane = threadIdx.x & 63;
    int j = lane * 8;
    float4 va = *(const float4*)&h1raw[j];
    float4 vb = *(const float4*)&h1raw[j + 4];
    float s = va.x + va.y + va.z + va.w + vb.x + vb.y + vb.z + vb.w;
    for (int off = 32; off; off >>= 1) s += __shfl_xor(s, off);
    float mu = s * (1.0f / PD);
    float dx[8];
    dx[0]=va.x-mu; dx[1]=va.y-mu; dx[2]=va.z-mu; dx[3]=va.w-mu;
    dx[4]=vb.x-mu; dx[5]=vb.y-mu; dx[6]=vb.z-mu; dx[7]=vb.w-mu;
    float s2 = 0.f;
#pragma unroll
    for (int i = 0; i < 8; ++i) s2 += dx[i] * dx[i];
    for (int off = 32; off; off >>= 1) s2 += __shfl_xor(s2, off);
    float rstd = rsqrtf(s2 * (1.0f / PD) + LN_EPS);
    float4 lw0 = *(const float4*)&lnw[j], lw1 = *(const float4*)&lnw[j + 4];
    float4 lb0 = *(const float4*)&lnb[j], lb1 = *(const float4*)&lnb[j + 4];
    float hln[8];
    hln[0]=fmaxf(dx[0]*rstd*lw0.x+lb0.x,0.f); hln[1]=fmaxf(dx[1]*rstd*lw0.y+lb0.y,0.f);
    hln[2]=fmaxf(dx[2]*rstd*lw0.z+lb0.z,0.f); hln[3]=fmaxf(dx[3]*rstd*lw0.w+lb0.w,0.f);
    hln[4]=fmaxf(dx[4]*rstd*lw1.x+lb1.x,0.f); hln[5]=fmaxf(dx[5]*rstd*lw1.y+lb1.y,0.f);
    hln[6]=fmaxf(dx[6]*rstd*lw1.z+lb1.z,0.f); hln[7]=fmaxf(dx[7]*rstd*lw1.w+lb1.w,0.f);
    const float* w = Wp2 + (size_t)row * PD + j;
    float4 w0 = *(const float4*)w, w1 = *(const float4*)(w + 4);
    float acc = w0.x*hln[0] + w0.y*hln[1] + w0.z*hln[2] + w0.w*hln[3]
              + w1.x*hln[4] + w1.y*hln[5] + w1.z*hln[6] + w1.w*hln[7];
    for (int off = 32; off; off >>= 1) acc += __shfl_xor(acc, off);
    if (lane == 0) x1f[row] = acc + bp2[row];
}

// out[s][j] = x[s][j] + x1f[j]; 2 float4/thread
__global__ __launch_bounds__(256) void k_out(const float* __restrict__ x,
                                             const float* __restrict__ x1f,
                                             float* __restrict__ out) {
    size_t i = (size_t)blockIdx.x * 512 + threadIdx.x;
    float4 xv = ((const float4*)x)[i];
    float4 a  = ((const float4*)x1f)[(int)(i & 511)];
    ((float4*)out)[i] = make_float4(xv.x + a.x, xv.y + a.y, xv.z + a.z, xv.w + a.w);
    size_t i2 = i + 256;
    float4 xv2 = ((const float4*)x)[i2];
    float4 a2  = ((const float4*)x1f)[(int)(i2 & 511)];
    ((float4*)out)[i2] = make_float4(xv2.x + a2.x, xv2.y + a2.y, xv2.z + a2.z, xv2.w + a2.w);
}

extern "C" void kernel_launch(void* const* d_in, const int* in_sizes, int n_in,
                              void* d_out, int out_size, void* d_ws, size_t ws_size,
                              hipStream_t stream) {
    const float* x    = (const float*)d_in[0];
    const float* q    = (const float*)d_in[1];
    const float* Wkv  = (const float*)d_in[2];
    const float* bkv  = (const float*)d_in[3];
    const float* Wp1  = (const float*)d_in[4];
    const float* bp1  = (const float*)d_in[5];
    const float* Wp2  = (const float*)d_in[6];
    const float* bp2  = (const float*)d_in[7];
    const float* lnw  = (const float*)d_in[8];
    const float* lnb  = (const float*)d_in[9];
    float* out = (float*)d_out;
    float* ws  = (float*)d_ws;

    float*  qb    = ws + OFF_QB;
    float*  smp   = ws + OFF_SMP;
    __bf16* qWb   = (__bf16*)(ws + OFF_QWB);
    float*  pctx  = ws + OFF_PCTX;
    float*  ctx   = ws + OFF_CTX;
    float*  x1    = ws + OFF_X1;
    float*  h1raw = ws + OFF_H1R;
    float*  x1f   = ws + OFF_X1F;

    k_prep  <<<256, 256, 0, stream>>>(q, Wkv, bkv, qWb, qb, smp);
    k_attn  <<<256, 256, 0, stream>>>(x, qWb, qb, pctx, smp);
    k_ctxred<<<128, 256, 0, stream>>>(pctx, smp, ctx);
    k_x1    <<<512, 256, 0, stream>>>(Wkv, bkv, ctx, x1);
    k_h1    <<<128, 256, 0, stream>>>(Wp1, bp1, x1, h1raw);
    k_x1f   <<<512, 256, 0, stream>>>(Wp2, bp2, h1raw, lnw, lnb, x1f);
    k_out   <<<8192, 256, 0, stream>>>(x, x1f, out);
}